// Round 1
// baseline (656.766 us; speedup 1.0000x reference)
//
#include <hip/hip_runtime.h>

#define N_RAYS 262144
#define N_SAMPLES 128

// One wave (64 lanes) per ray. Lane i handles samples 2i, 2i+1.
// Affine-compose locally, then ordered shfl_down tree reduce (offsets 1..32).
__global__ __launch_bounds__(256) void composite_kernel(
    const float4* __restrict__ in, float* __restrict__ out) {
    const int tid  = threadIdx.x;
    const int wave = tid >> 6;        // 0..3 within block
    const int lane = tid & 63;
    const int ray  = blockIdx.x * 4 + wave;

    const float4* p = in + (size_t)ray * N_SAMPLES;

    // Two float4 loads: lane-stride 32B, together covering the ray's 2KB.
    float4 v0 = p[2 * lane];
    float4 v1 = p[2 * lane + 1];

    // Local composite of the two consecutive samples (front-to-back):
    //   map(t) = A + O * t, with A = a0*rgb0 + (1-a0)*a1*rgb1, O = (1-a0)(1-a1)
    const float a0 = v0.x, a1 = v1.x;
    const float o0 = 1.0f - a0;
    const float w1 = o0 * a1;
    float Ar = fmaf(w1, v1.y, a0 * v0.y);
    float Ag = fmaf(w1, v1.z, a0 * v0.z);
    float Ab = fmaf(w1, v1.w, a0 * v0.w);
    float O  = o0 * (1.0f - a1);

    // Ordered tree reduction across the wave (non-commutative affine compose):
    // after step with offset k, lane i holds segment [i, i + 2k).
    #pragma unroll
    for (int off = 1; off <= 32; off <<= 1) {
        float Ar2 = __shfl_down(Ar, off, 64);
        float Ag2 = __shfl_down(Ag, off, 64);
        float Ab2 = __shfl_down(Ab, off, 64);
        float O2  = __shfl_down(O,  off, 64);
        Ar = fmaf(O, Ar2, Ar);
        Ag = fmaf(O, Ag2, Ag);
        Ab = fmaf(O, Ab2, Ab);
        O *= O2;
    }

    if (lane == 0) {
        float* o = out + (size_t)ray * 3;
        o[0] = Ar;
        o[1] = Ag;
        o[2] = Ab;
    }
}

extern "C" void kernel_launch(void* const* d_in, const int* in_sizes, int n_in,
                              void* d_out, int out_size, void* d_ws, size_t ws_size,
                              hipStream_t stream) {
    const float4* in = (const float4*)d_in[0];
    float* out = (float*)d_out;
    composite_kernel<<<N_RAYS / 4, 256, 0, stream>>>(in, out);
}

// Round 2
// 586.540 us; speedup vs baseline: 1.1197x; 1.1197x over previous
//
#include <hip/hip_runtime.h>

#define N_RAYS 262144
#define N_SAMPLES 128
#define CHUNK 32
#define TERM_EPS 1e-3f
// Early ray termination: alpha ~ U[0,1) => -ln O_32 ~ Gamma(32,1); max O_32 over
// 262k rays ~ e^-13 ~ 2e-6. Dropped-tail abs error <= O * 1 <= TERM_EPS << 2e-2.

__global__ __launch_bounds__(256) void composite_kernel(
    const float4* __restrict__ in, float* __restrict__ out) {
    const int tid  = threadIdx.x;
    const int lane = tid & 63;
    const int half = lane >> 5;          // which ray within the wave
    const int l32  = lane & 31;
    const int wave = tid >> 6;           // 0..3 within block
    const int ray  = blockIdx.x * 8 + wave * 2 + half;

    const float4* p = in + (size_t)ray * N_SAMPLES;
    const int leader = half << 5;        // lane 0 or 32

    // running composite map (uniform within each half): t -> A + O*t
    float Ar = 0.f, Ag = 0.f, Ab = 0.f, O = 1.f;

    #pragma unroll 1   // do NOT unroll: loads of later chunks must stay behind the break
    for (int c = 0; c < N_SAMPLES / CHUNK; ++c) {
        // lanes 0-31: ray's samples [c*32, c*32+32) -> contiguous 512B
        // lanes 32-63: next ray's same range (base +2KB) -> contiguous 512B
        float4 v = p[c * CHUNK + l32];
        float a  = v.x;
        float ar = a * v.y, ag = a * v.z, ab = a * v.w;
        float o  = 1.0f - a;

        // ordered affine-compose tree within each 32-lane half:
        // after step off=k, lane i holds segment [i, i+2k)
        #pragma unroll
        for (int off = 1; off <= 16; off <<= 1) {
            float ar2 = __shfl_down(ar, off, 32);
            float ag2 = __shfl_down(ag, off, 32);
            float ab2 = __shfl_down(ab, off, 32);
            float o2  = __shfl_down(o,  off, 32);
            ar = fmaf(o, ar2, ar);
            ag = fmaf(o, ag2, ag);
            ab = fmaf(o, ab2, ab);
            o *= o2;
        }

        // leaders (lane 0 / 32) hold the chunk map; broadcast within the half
        float car = __shfl(ar, leader, 64);
        float cag = __shfl(ag, leader, 64);
        float cab = __shfl(ab, leader, 64);
        float co  = __shfl(o,  leader, 64);

        Ar = fmaf(O, car, Ar);
        Ag = fmaf(O, cag, Ag);
        Ab = fmaf(O, cab, Ab);
        O *= co;

        // wave-uniform early exit once both rays' transmittance is negligible
        if (__ballot(O >= TERM_EPS) == 0ull) break;
    }

    if (l32 == 0) {
        float* o3 = out + (size_t)ray * 3;
        o3[0] = Ar;
        o3[1] = Ag;
        o3[2] = Ab;
    }
}

extern "C" void kernel_launch(void* const* d_in, const int* in_sizes, int n_in,
                              void* d_out, int out_size, void* d_ws, size_t ws_size,
                              hipStream_t stream) {
    const float4* in = (const float4*)d_in[0];
    float* out = (float*)d_out;
    composite_kernel<<<N_RAYS / 8, 256, 0, stream>>>(in, out);
}

// Round 3
// 573.578 us; speedup vs baseline: 1.1450x; 1.0226x over previous
//
#include <hip/hip_runtime.h>

#define N_RAYS 262144
#define N_SAMPLES 128
#define CHUNK 16
#define TERM_EPS 1e-3f
// Early ray termination is data-driven: a ray's tail is dropped only after its
// measured transmittance O < TERM_EPS, so per-ray abs error <= O*max(rgb) < 1e-3
// << 2e-2 threshold. With alpha~U[0,1), P(O_16 >= 1e-3) ~ 2e-3, so ~97% of waves
// read exactly 16 samples/ray (64 MiB total instead of 512 MiB).

__global__ __launch_bounds__(256) void composite_kernel(
    const float4* __restrict__ in, float* __restrict__ out) {
    const int tid  = threadIdx.x;
    const int lane = tid & 63;
    const int l16  = lane & 15;          // lane within 16-lane segment
    const int ray  = blockIdx.x * 16 + (tid >> 4);   // 4 rays per wave

    const float4* p = in + (size_t)ray * N_SAMPLES;
    const int leader = lane & 48;        // segment leader lane (0/16/32/48)

    // running composite map (uniform within each segment): t -> A + O*t
    float Ar = 0.f, Ag = 0.f, Ab = 0.f, O = 1.f;

    #pragma unroll 1   // keep later chunk loads behind the break
    for (int c = 0; c < N_SAMPLES / CHUNK; ++c) {
        // each 16-lane segment reads 256B contiguous from its ray
        float4 v = p[c * CHUNK + l16];
        float a  = v.x;
        float ar = a * v.y, ag = a * v.z, ab = a * v.w;
        float o  = 1.0f - a;

        // ordered affine-compose tree within the 16-lane segment:
        // after step off=k, lane i holds segment [i, i+2k)
        #pragma unroll
        for (int off = 1; off <= 8; off <<= 1) {
            float ar2 = __shfl_down(ar, off, 16);
            float ag2 = __shfl_down(ag, off, 16);
            float ab2 = __shfl_down(ab, off, 16);
            float o2  = __shfl_down(o,  off, 16);
            ar = fmaf(o, ar2, ar);
            ag = fmaf(o, ag2, ag);
            ab = fmaf(o, ab2, ab);
            o *= o2;
        }

        // broadcast the segment-composite from the leader lane
        float car = __shfl(ar, leader, 64);
        float cag = __shfl(ag, leader, 64);
        float cab = __shfl(ab, leader, 64);
        float co  = __shfl(o,  leader, 64);

        Ar = fmaf(O, car, Ar);
        Ag = fmaf(O, cag, Ag);
        Ab = fmaf(O, cab, Ab);
        O *= co;

        // wave-uniform early exit once all 4 rays' transmittance is negligible
        if (__ballot(O >= TERM_EPS) == 0ull) break;
    }

    if (l16 == 0) {
        float* o3 = out + (size_t)ray * 3;
        o3[0] = Ar;
        o3[1] = Ag;
        o3[2] = Ab;
    }
}

extern "C" void kernel_launch(void* const* d_in, const int* in_sizes, int n_in,
                              void* d_out, int out_size, void* d_ws, size_t ws_size,
                              hipStream_t stream) {
    const float4* in = (const float4*)d_in[0];
    float* out = (float*)d_out;
    composite_kernel<<<N_RAYS / 16, 256, 0, stream>>>(in, out);
}